// Round 1
// baseline (118.708 us; speedup 1.0000x reference)
//
#include <hip/hip_runtime.h>
#include <stdint.h>

#define R_NUM 4096
#define D_DIM 64
#define DEG_N 6
#define MF 8

// Classify the on-device encoding of the bool mask buffer by inspecting the
// first 1024 32-bit words (safe to read under every candidate encoding:
// uint8 -> 4096 B, int32 -> 16 KB, etc.).
//  flag: 0 = 1-byte bool, 1 = int32, 2 = int64, 3 = float32
__global__ void detect_mask_kernel(const uint32_t* __restrict__ w,
                                   int* __restrict__ flag) {
  if (blockIdx.x != 0 || threadIdx.x != 0) return;
  bool all_int01 = true, all_f01 = true, odd_zero = true, any_even_one = false;
  for (int i = 0; i < 1024; ++i) {
    uint32_t v = w[i];
    all_int01 = all_int01 && (v <= 1u);
    all_f01 = all_f01 && (v == 0u || v == 0x3f800000u);
    if (i & 1) odd_zero = odd_zero && (v == 0u);
    else       any_even_one = any_even_one || (v == 1u);
  }
  int f = 0;                                    // default: 1-byte bool
  if (all_int01) f = (odd_zero && any_even_one) ? 2 : 1;  // int64 : int32
  else if (all_f01) f = 3;                      // float32 0.0/1.0
  *flag = f;
}

// One block per destination region r. Edges 6r..6r+5 all have dst == r
// (dst = repeat(arange(R), 6)), so the segment-sum is a private accumulate.
//
// W-tile read pattern: thread t, chunk c reads float4 at flat index
// c*1024 + 4t of the 64x64 edge matrix -> wave-contiguous 1 KB transactions.
// That float4 belongs to output row i = 16c + (t>>4), cols 4(t&15)..+3.
// Weights are folded into h, so a single 16-lane xor-butterfly at the end
// reduces each row across its 16 owning lanes.
__launch_bounds__(256)
__global__ void router_kernel(const float* __restrict__ H,
                              const void* __restrict__ mask_raw,
                              const float* __restrict__ coords,
                              const float* __restrict__ W_edges,
                              const float* __restrict__ W_reg,
                              const float* __restrict__ beta_cos,
                              const float* __restrict__ beta_sin,
                              const int* __restrict__ src,
                              const int* __restrict__ flag_p,
                              float* __restrict__ out) {
  const int r = blockIdx.x;
  const int t = threadIdx.x;
  const int q = t >> 4;          // row sub-index within each 16-row chunk
  const int j0 = (t & 15) << 2;  // starting col of this lane's float4

  __shared__ float s_w[DEG_N];
  __shared__ int s_src[DEG_N];

  if (t < DEG_N) {
    const int e = r * DEG_N + t;
    const int s = src[e];
    s_src[t] = s;
    const float dx = coords[2 * r] - coords[2 * s];
    const float dy = coords[2 * r + 1] - coords[2 * s + 1];
    float b = 0.f;
#pragma unroll
    for (int m = 0; m < MF; ++m) {
      const float S = dx * W_reg[2 * m] + dy * W_reg[2 * m + 1];
      float sv, cv;
      __sincosf(S, &sv, &cv);
      b += cv * beta_cos[m] + sv * beta_sin[m];
    }
    const int mflag = *flag_p;
    bool mv;
    if (mflag == 1)      mv = ((const int*)mask_raw)[s] != 0;
    else if (mflag == 2) mv = ((const long long*)mask_raw)[s] != 0;
    else if (mflag == 3) mv = ((const float*)mask_raw)[s] != 0.f;
    else                 mv = ((const uint8_t*)mask_raw)[s] != 0;
    // w = mask * (1 + FB_ALPHA * FB_SCALE * b),  0.1 / sqrt(8)
    s_w[t] = mv ? fmaf(0.035355339059327376f, b, 1.0f) : 0.f;
  }
  __syncthreads();

  const float* __restrict__ Wb =
      W_edges + (size_t)r * (DEG_N * D_DIM * D_DIM);

  float p0 = 0.f, p1 = 0.f, p2 = 0.f, p3 = 0.f;
#pragma unroll
  for (int k = 0; k < DEG_N; ++k) {
    const int s = s_src[k];
    const float w = s_w[k];
    float4 hv = *reinterpret_cast<const float4*>(&H[s * D_DIM + j0]);
    hv.x *= w; hv.y *= w; hv.z *= w; hv.w *= w;  // fold edge weight into h
    const float* We = Wb + k * (D_DIM * D_DIM);
    const float4 w0 = *reinterpret_cast<const float4*>(&We[t * 4]);
    const float4 w1 = *reinterpret_cast<const float4*>(&We[1024 + t * 4]);
    const float4 w2 = *reinterpret_cast<const float4*>(&We[2048 + t * 4]);
    const float4 w3 = *reinterpret_cast<const float4*>(&We[3072 + t * 4]);
    p0 += w0.x * hv.x + w0.y * hv.y + w0.z * hv.z + w0.w * hv.w;
    p1 += w1.x * hv.x + w1.y * hv.y + w1.z * hv.z + w1.w * hv.w;
    p2 += w2.x * hv.x + w2.y * hv.y + w2.z * hv.z + w2.w * hv.w;
    p3 += w3.x * hv.x + w3.y * hv.y + w3.z * hv.z + w3.w * hv.w;
  }
  // reduce across the 16 lanes owning each row (xor masks stay in-group)
#pragma unroll
  for (int off = 1; off < 16; off <<= 1) {
    p0 += __shfl_xor(p0, off);
    p1 += __shfl_xor(p1, off);
    p2 += __shfl_xor(p2, off);
    p3 += __shfl_xor(p3, off);
  }
  if ((t & 15) == 0) {
    float* o = out + r * D_DIM;
    o[q]      = p0;
    o[16 + q] = p1;
    o[32 + q] = p2;
    o[48 + q] = p3;
  }
}

extern "C" void kernel_launch(void* const* d_in, const int* in_sizes, int n_in,
                              void* d_out, int out_size, void* d_ws, size_t ws_size,
                              hipStream_t stream) {
  const float* H        = (const float*)d_in[0];
  const void*  mask     = d_in[1];
  const float* coords   = (const float*)d_in[2];
  const float* W_edges  = (const float*)d_in[3];
  const float* W_reg    = (const float*)d_in[4];
  const float* beta_cos = (const float*)d_in[5];
  const float* beta_sin = (const float*)d_in[6];
  const int*   src      = (const int*)d_in[7];
  // d_in[8] (dst) is structurally repeat(arange(R), 6); not needed.
  int* flag = (int*)d_ws;

  detect_mask_kernel<<<1, 64, 0, stream>>>((const uint32_t*)mask, flag);
  router_kernel<<<R_NUM, 256, 0, stream>>>(H, mask, coords, W_edges, W_reg,
                                           beta_cos, beta_sin, src, flag,
                                           (float*)d_out);
}

// Round 2
// 75.459 us; speedup vs baseline: 1.5731x; 1.5731x over previous
//
#include <hip/hip_runtime.h>
#include <stdint.h>

#define R_NUM 4096
#define D_DIM 64
#define DEG_N 6
#define MF 8
#define FB_COEF 0.035355339059327376f  // FB_ALPHA * FB_SCALE = 0.1/sqrt(8)

// One block per destination region r (dst = repeat(arange(R), 6) -> edges
// 6r..6r+5 all land in region r; segment-sum is a private accumulate).
//
// 1024 threads: thread t owns output row q = t>>4, cols j0..j0+3 of every
// edge matrix. W read pattern: thread t reads float4 at flat index 4t of
// each 64x64 matrix -> each wave issues one contiguous 1 KB transaction per
// edge. Only 6 W loads/thread -> low VGPR -> 2 blocks/CU (32 waves/CU).
//
// No __syncthreads anywhere: mask-dtype detection is a per-wave ballot and
// edge weights are computed by lanes 0..5 of each wave, then __shfl-bcast.
__launch_bounds__(1024, 8)
__global__ void router_kernel(const float* __restrict__ H,
                              const void* __restrict__ mask_raw,
                              const float* __restrict__ coords,
                              const float* __restrict__ W_edges,
                              const float* __restrict__ W_reg,
                              const float* __restrict__ beta_cos,
                              const float* __restrict__ beta_sin,
                              const int* __restrict__ src,
                              float* __restrict__ out) {
  const int r    = blockIdx.x;
  const int t    = threadIdx.x;
  const int lane = t & 63;
  const int q    = t >> 4;          // output row 0..63
  const int j0   = (t & 15) << 2;   // starting col of this lane's float4

  // ---- per-wave mask-dtype detection over the first 256 words (1 KB).
  // Safe to read under every candidate encoding (bool buffer = 4 KB).
  //  flag: 0 = 1-byte bool, 1 = int32, 2 = int64, 3 = float32
  const uint32_t* mw = (const uint32_t*)mask_raw;
  bool int01 = true, f01 = true, oddz = true, even1 = false;
#pragma unroll
  for (int i = 0; i < 4; ++i) {
    const int idx = lane + 64 * i;        // parity of idx == parity of lane
    const uint32_t v = mw[idx];
    int01 = int01 && (v <= 1u);
    f01   = f01 && (v == 0u || v == 0x3f800000u);
    if (lane & 1) oddz = oddz && (v == 0u);
    else          even1 = even1 || (v == 1u);
  }
  const bool all_int01 = (__ballot(int01) == ~0ULL);
  const bool all_f01   = (__ballot(f01)   == ~0ULL);
  const bool all_oddz  = (__ballot(!oddz) == 0ULL);
  const bool any_even1 = (__ballot(even1) != 0ULL);
  int mflag = 0;
  if (all_int01)    mflag = (all_oddz && any_even1) ? 2 : 1;
  else if (all_f01) mflag = 3;

  // ---- lanes 0..5 of each wave compute their edge's scalar weight ----
  float wq = 0.f;
  int   sq = 0;
  if (lane < DEG_N) {
    const int e = r * DEG_N + lane;
    const int s = src[e];
    sq = s;
    const float dx = coords[2 * r]     - coords[2 * s];
    const float dy = coords[2 * r + 1] - coords[2 * s + 1];
    float b = 0.f;
#pragma unroll
    for (int m = 0; m < MF; ++m) {
      const float S = dx * W_reg[2 * m] + dy * W_reg[2 * m + 1];
      float sv, cv;
      __sincosf(S, &sv, &cv);
      b += cv * beta_cos[m] + sv * beta_sin[m];
    }
    bool mv;
    if (mflag == 1)      mv = ((const int*)mask_raw)[s] != 0;
    else if (mflag == 2) mv = ((const long long*)mask_raw)[s] != 0;
    else if (mflag == 3) mv = ((const float*)mask_raw)[s] != 0.f;
    else                 mv = ((const uint8_t*)mask_raw)[s] != 0;
    wq = mv ? fmaf(FB_COEF, b, 1.0f) : 0.f;
  }

  // ---- main streaming loop: 6 independent 16B W loads per thread ----
  const float* __restrict__ Wb = W_edges + (size_t)r * (DEG_N * D_DIM * D_DIM);
  float p = 0.f;
#pragma unroll
  for (int k = 0; k < DEG_N; ++k) {
    const int   s = __shfl(sq, k);
    const float w = __shfl(wq, k);
    const float4 wv = *reinterpret_cast<const float4*>(Wb + k * (D_DIM * D_DIM) + t * 4);
    const float4 hv = *reinterpret_cast<const float4*>(&H[s * D_DIM + j0]);
    p = fmaf(w, wv.x * hv.x + wv.y * hv.y + wv.z * hv.z + wv.w * hv.w, p);
  }

  // ---- reduce across the 16 lanes owning each row ----
#pragma unroll
  for (int off = 1; off < 16; off <<= 1) p += __shfl_xor(p, off);

  // lanes 0,16,32,48 of each wave hold rows 4w..4w+3; compact into one
  // float4 store from lane 0 of the wave.
  const float p0 = __shfl(p, 0);
  const float p1 = __shfl(p, 16);
  const float p2 = __shfl(p, 32);
  const float p3 = __shfl(p, 48);
  if (lane == 0) {
    float4 o = make_float4(p0, p1, p2, p3);
    *reinterpret_cast<float4*>(&out[r * D_DIM + (q & ~3)]) = o;
  }
}

extern "C" void kernel_launch(void* const* d_in, const int* in_sizes, int n_in,
                              void* d_out, int out_size, void* d_ws, size_t ws_size,
                              hipStream_t stream) {
  const float* H        = (const float*)d_in[0];
  const void*  mask     = d_in[1];
  const float* coords   = (const float*)d_in[2];
  const float* W_edges  = (const float*)d_in[3];
  const float* W_reg    = (const float*)d_in[4];
  const float* beta_cos = (const float*)d_in[5];
  const float* beta_sin = (const float*)d_in[6];
  const int*   src      = (const int*)d_in[7];
  // d_in[8] (dst) is structurally repeat(arange(R), 6); not needed.

  router_kernel<<<R_NUM, 1024, 0, stream>>>(H, mask, coords, W_edges, W_reg,
                                            beta_cos, beta_sin, src,
                                            (float*)d_out);
}

// Round 4
// 71.655 us; speedup vs baseline: 1.6567x; 1.0531x over previous
//
#include <hip/hip_runtime.h>
#include <stdint.h>

#define R_NUM 4096
#define D_DIM 64
#define DEG_N 6
#define MF 8
#define FB_COEF 0.035355339059327376f  // FB_ALPHA * FB_SCALE = 0.1/sqrt(8)

// Native clang vector type: __builtin_nontemporal_load requires a pointer to
// scalar/vector-of-scalar, not HIP's struct float4.
typedef float f4v __attribute__((ext_vector_type(4)));

// One block per destination region r (dst = repeat(arange(R), 6) -> edges
// 6r..6r+5 all land in region r; segment-sum is a private accumulate).
//
// 1024 threads: thread t owns output row q = t>>4, cols j0..j0+3 of every
// edge matrix. W read pattern: thread t reads float4 at flat index 4t of
// each 64x64 matrix -> each wave issues one contiguous 1 KB transaction per
// edge. All 6 W loads are issued FIRST (independent of everything) and are
// NON-TEMPORAL: W is 403 MB touched exactly once -- evict-first keeps L2
// for H/coords/mask, which every block re-reads.
//
// No __syncthreads anywhere: mask-dtype detection is a per-wave ballot and
// edge weights are computed by lanes 0..5 of each wave, then __shfl-bcast.
__launch_bounds__(1024, 8)
__global__ void router_kernel(const float* __restrict__ H,
                              const void* __restrict__ mask_raw,
                              const float* __restrict__ coords,
                              const float* __restrict__ W_edges,
                              const float* __restrict__ W_reg,
                              const float* __restrict__ beta_cos,
                              const float* __restrict__ beta_sin,
                              const int* __restrict__ src,
                              float* __restrict__ out) {
  const int r    = blockIdx.x;
  const int t    = threadIdx.x;
  const int lane = t & 63;
  const int q    = t >> 4;          // output row 0..63
  const int j0   = (t & 15) << 2;   // starting col of this lane's float4

  // ---- issue the 6 HBM-critical W loads immediately (nontemporal) ----
  const float* __restrict__ Wb = W_edges + (size_t)r * (DEG_N * D_DIM * D_DIM);
  const f4v wv0 = __builtin_nontemporal_load(
      reinterpret_cast<const f4v*>(Wb + 0 * (D_DIM * D_DIM) + t * 4));
  const f4v wv1 = __builtin_nontemporal_load(
      reinterpret_cast<const f4v*>(Wb + 1 * (D_DIM * D_DIM) + t * 4));
  const f4v wv2 = __builtin_nontemporal_load(
      reinterpret_cast<const f4v*>(Wb + 2 * (D_DIM * D_DIM) + t * 4));
  const f4v wv3 = __builtin_nontemporal_load(
      reinterpret_cast<const f4v*>(Wb + 3 * (D_DIM * D_DIM) + t * 4));
  const f4v wv4 = __builtin_nontemporal_load(
      reinterpret_cast<const f4v*>(Wb + 4 * (D_DIM * D_DIM) + t * 4));
  const f4v wv5 = __builtin_nontemporal_load(
      reinterpret_cast<const f4v*>(Wb + 5 * (D_DIM * D_DIM) + t * 4));

  // ---- per-wave mask-dtype detection over the first 256 words (1 KB).
  // Safe to read under every candidate encoding (bool buffer = 4 KB).
  //  flag: 0 = 1-byte bool, 1 = int32, 2 = int64, 3 = float32
  const uint32_t* mw = (const uint32_t*)mask_raw;
  bool int01 = true, f01 = true, oddz = true, even1 = false;
#pragma unroll
  for (int i = 0; i < 4; ++i) {
    const int idx = lane + 64 * i;        // parity of idx == parity of lane
    const uint32_t v = mw[idx];
    int01 = int01 && (v <= 1u);
    f01   = f01 && (v == 0u || v == 0x3f800000u);
    if (lane & 1) oddz = oddz && (v == 0u);
    else          even1 = even1 || (v == 1u);
  }
  const bool all_int01 = (__ballot(int01) == ~0ULL);
  const bool all_f01   = (__ballot(f01)   == ~0ULL);
  const bool all_oddz  = (__ballot(!oddz) == 0ULL);
  const bool any_even1 = (__ballot(even1) != 0ULL);
  int mflag = 0;
  if (all_int01)    mflag = (all_oddz && any_even1) ? 2 : 1;
  else if (all_f01) mflag = 3;

  // ---- lanes 0..5 of each wave compute their edge's scalar weight ----
  float wq = 0.f;
  int   sq = 0;
  if (lane < DEG_N) {
    const int e = r * DEG_N + lane;
    const int s = src[e];
    sq = s;
    const float dx = coords[2 * r]     - coords[2 * s];
    const float dy = coords[2 * r + 1] - coords[2 * s + 1];
    float b = 0.f;
#pragma unroll
    for (int m = 0; m < MF; ++m) {
      const float S = dx * W_reg[2 * m] + dy * W_reg[2 * m + 1];
      float sv, cv;
      __sincosf(S, &sv, &cv);
      b += cv * beta_cos[m] + sv * beta_sin[m];
    }
    bool mv;
    if (mflag == 1)      mv = ((const int*)mask_raw)[s] != 0;
    else if (mflag == 2) mv = ((const long long*)mask_raw)[s] != 0;
    else if (mflag == 3) mv = ((const float*)mask_raw)[s] != 0.f;
    else                 mv = ((const uint8_t*)mask_raw)[s] != 0;
    wq = mv ? fmaf(FB_COEF, b, 1.0f) : 0.f;
  }

  // ---- accumulate: h-gather (L1/L2-resident) x streamed W ----
  float p = 0.f;
#define EDGE(k, wv)                                                          \
  {                                                                          \
    const int   s = __shfl(sq, k);                                           \
    const float w = __shfl(wq, k);                                           \
    const float4 hv = *reinterpret_cast<const float4*>(&H[s * D_DIM + j0]);  \
    p = fmaf(w, wv.x * hv.x + wv.y * hv.y + wv.z * hv.z + wv.w * hv.w, p);   \
  }
  EDGE(0, wv0) EDGE(1, wv1) EDGE(2, wv2)
  EDGE(3, wv3) EDGE(4, wv4) EDGE(5, wv5)
#undef EDGE

  // ---- reduce across the 16 lanes owning each row ----
#pragma unroll
  for (int off = 1; off < 16; off <<= 1) p += __shfl_xor(p, off);

  // lanes 0,16,32,48 of each wave hold rows 4w..4w+3; compact into one
  // float4 store from lane 0 of the wave.
  const float p0 = __shfl(p, 0);
  const float p1 = __shfl(p, 16);
  const float p2 = __shfl(p, 32);
  const float p3 = __shfl(p, 48);
  if (lane == 0) {
    float4 o = make_float4(p0, p1, p2, p3);
    *reinterpret_cast<float4*>(&out[r * D_DIM + (q & ~3)]) = o;
  }
}

extern "C" void kernel_launch(void* const* d_in, const int* in_sizes, int n_in,
                              void* d_out, int out_size, void* d_ws, size_t ws_size,
                              hipStream_t stream) {
  const float* H        = (const float*)d_in[0];
  const void*  mask     = d_in[1];
  const float* coords   = (const float*)d_in[2];
  const float* W_edges  = (const float*)d_in[3];
  const float* W_reg    = (const float*)d_in[4];
  const float* beta_cos = (const float*)d_in[5];
  const float* beta_sin = (const float*)d_in[6];
  const int*   src      = (const int*)d_in[7];
  // d_in[8] (dst) is structurally repeat(arange(R), 6); not needed.

  router_kernel<<<R_NUM, 1024, 0, stream>>>(H, mask, coords, W_edges, W_reg,
                                            beta_cos, beta_sin, src,
                                            (float*)d_out);
}

// Round 6
// 70.746 us; speedup vs baseline: 1.6779x; 1.0128x over previous
//
#include <hip/hip_runtime.h>
#include <stdint.h>

#define R_NUM 4096
#define D_DIM 64
#define DEG_N 6
#define MF 8
#define FB_COEF 0.035355339059327376f  // FB_ALPHA * FB_SCALE = 0.1/sqrt(8)

// Native clang vector type: __builtin_nontemporal_load requires a pointer to
// scalar/vector-of-scalar, not HIP's struct float4.
typedef float f4v __attribute__((ext_vector_type(4)));

// One block per destination region r (dst = repeat(arange(R), 6) -> edges
// 6r..6r+5 all land in region r; segment-sum is a private accumulate).
//
// R5 change: the mask-dtype ballot + sincos edge-weight prologue used to run
// in EVERY wave (~150 issue-slots x 65536 waves ~= 8 us of pure VALU issue).
// Now wave 0 computes the block's 6 edge weights once, publishes via 48 B of
// LDS, and all waves read them as block-uniform scalars after one
// __syncthreads(). W loads are issued AFTER the barrier so the barrier's
// vmcnt drain serializes nothing (non-wave-0 waves have no outstanding ops).
//
// W read pattern: thread t reads float4 at flat index 4t of each 64x64 edge
// matrix -> each wave issues one contiguous 1 KB transaction per edge, all
// NON-TEMPORAL (W is 403 MB touched exactly once; keep L2 for H/coords).
__launch_bounds__(1024, 8)
__global__ void router_kernel(const float* __restrict__ H,
                              const void* __restrict__ mask_raw,
                              const float* __restrict__ coords,
                              const float* __restrict__ W_edges,
                              const float* __restrict__ W_reg,
                              const float* __restrict__ beta_cos,
                              const float* __restrict__ beta_sin,
                              const int* __restrict__ src,
                              float* __restrict__ out) {
  const int r    = blockIdx.x;
  const int t    = threadIdx.x;
  const int lane = t & 63;
  const int q    = t >> 4;          // output row 0..63
  const int j0   = (t & 15) << 2;   // starting col of this lane's float4

  __shared__ float s_w[DEG_N];
  __shared__ int   s_src[DEG_N];

  if (t < 64) {  // wave 0 only: detection + edge weights
    // -- mask-dtype detection over the first 256 words (1 KB; safe under
    //    every candidate encoding since the bool buffer is 4 KB).
    //    flag: 0 = 1-byte bool, 1 = int32, 2 = int64, 3 = float32
    const uint32_t* mw = (const uint32_t*)mask_raw;
    bool int01 = true, f01 = true, oddz = true, even1 = false;
#pragma unroll
    for (int i = 0; i < 4; ++i) {
      const int idx = lane + 64 * i;      // parity of idx == parity of lane
      const uint32_t v = mw[idx];
      int01 = int01 && (v <= 1u);
      f01   = f01 && (v == 0u || v == 0x3f800000u);
      if (lane & 1) oddz = oddz && (v == 0u);
      else          even1 = even1 || (v == 1u);
    }
    const bool all_int01 = (__ballot(int01) == ~0ULL);
    const bool all_f01   = (__ballot(f01)   == ~0ULL);
    const bool all_oddz  = (__ballot(!oddz) == 0ULL);
    const bool any_even1 = (__ballot(even1) != 0ULL);
    int mflag = 0;
    if (all_int01)    mflag = (all_oddz && any_even1) ? 2 : 1;
    else if (all_f01) mflag = 3;

    if (lane < DEG_N) {
      const int e = r * DEG_N + lane;
      const int s = src[e];
      const float dx = coords[2 * r]     - coords[2 * s];
      const float dy = coords[2 * r + 1] - coords[2 * s + 1];
      float b = 0.f;
#pragma unroll
      for (int m = 0; m < MF; ++m) {
        const float S = dx * W_reg[2 * m] + dy * W_reg[2 * m + 1];
        float sv, cv;
        __sincosf(S, &sv, &cv);
        b += cv * beta_cos[m] + sv * beta_sin[m];
      }
      bool mv;
      if (mflag == 1)      mv = ((const int*)mask_raw)[s] != 0;
      else if (mflag == 2) mv = ((const long long*)mask_raw)[s] != 0;
      else if (mflag == 3) mv = ((const float*)mask_raw)[s] != 0.f;
      else                 mv = ((const uint8_t*)mask_raw)[s] != 0;
      s_w[lane]   = mv ? fmaf(FB_COEF, b, 1.0f) : 0.f;
      s_src[lane] = s;
    }
  }
  __syncthreads();

  // ---- block-uniform edge params ----
  const int   s0 = s_src[0], s1 = s_src[1], s2 = s_src[2];
  const int   s3 = s_src[3], s4 = s_src[4], s5 = s_src[5];
  const float w0 = s_w[0], w1 = s_w[1], w2 = s_w[2];
  const float w3 = s_w[3], w4 = s_w[4], w5 = s_w[5];

  // ---- issue the 6 HBM-critical W loads (nontemporal, evict-first) ----
  const float* __restrict__ Wb = W_edges + (size_t)r * (DEG_N * D_DIM * D_DIM);
  const f4v wv0 = __builtin_nontemporal_load(
      reinterpret_cast<const f4v*>(Wb + 0 * (D_DIM * D_DIM) + t * 4));
  const f4v wv1 = __builtin_nontemporal_load(
      reinterpret_cast<const f4v*>(Wb + 1 * (D_DIM * D_DIM) + t * 4));
  const f4v wv2 = __builtin_nontemporal_load(
      reinterpret_cast<const f4v*>(Wb + 2 * (D_DIM * D_DIM) + t * 4));
  const f4v wv3 = __builtin_nontemporal_load(
      reinterpret_cast<const f4v*>(Wb + 3 * (D_DIM * D_DIM) + t * 4));
  const f4v wv4 = __builtin_nontemporal_load(
      reinterpret_cast<const f4v*>(Wb + 4 * (D_DIM * D_DIM) + t * 4));
  const f4v wv5 = __builtin_nontemporal_load(
      reinterpret_cast<const f4v*>(Wb + 5 * (D_DIM * D_DIM) + t * 4));

  // ---- accumulate: h-gather (L1/L2-resident) x streamed W ----
  // NOTE: macro params must not collide with vector component names
  // (a param named `w` would substitute into `hv.w`).
  float p = 0.f;
#define EDGE(ss, ww, vv)                                                     \
  {                                                                          \
    const float4 hv = *reinterpret_cast<const float4*>(&H[ss * D_DIM + j0]); \
    p = fmaf(ww, vv.x * hv.x + vv.y * hv.y + vv.z * hv.z + vv.w * hv.w, p);  \
  }
  EDGE(s0, w0, wv0) EDGE(s1, w1, wv1) EDGE(s2, w2, wv2)
  EDGE(s3, w3, wv3) EDGE(s4, w4, wv4) EDGE(s5, w5, wv5)
#undef EDGE

  // ---- reduce across the 16 lanes owning each row ----
#pragma unroll
  for (int off = 1; off < 16; off <<= 1) p += __shfl_xor(p, off);

  // lanes 0,16,32,48 of each wave hold rows 4w..4w+3; compact into one
  // float4 store from lane 0 of the wave.
  const float p0 = __shfl(p, 0);
  const float p1 = __shfl(p, 16);
  const float p2 = __shfl(p, 32);
  const float p3 = __shfl(p, 48);
  if (lane == 0) {
    float4 o = make_float4(p0, p1, p2, p3);
    *reinterpret_cast<float4*>(&out[r * D_DIM + (q & ~3)]) = o;
  }
}

extern "C" void kernel_launch(void* const* d_in, const int* in_sizes, int n_in,
                              void* d_out, int out_size, void* d_ws, size_t ws_size,
                              hipStream_t stream) {
  const float* H        = (const float*)d_in[0];
  const void*  mask     = d_in[1];
  const float* coords   = (const float*)d_in[2];
  const float* W_edges  = (const float*)d_in[3];
  const float* W_reg    = (const float*)d_in[4];
  const float* beta_cos = (const float*)d_in[5];
  const float* beta_sin = (const float*)d_in[6];
  const int*   src      = (const int*)d_in[7];
  // d_in[8] (dst) is structurally repeat(arange(R), 6); not needed.

  router_kernel<<<R_NUM, 1024, 0, stream>>>(H, mask, coords, W_edges, W_reg,
                                            beta_cos, beta_sin, src,
                                            (float*)d_out);
}